// Round 1
// 226.167 us; speedup vs baseline: 1.1402x; 1.1402x over previous
//
#include <hip/hip_runtime.h>
#include <hip/hip_bf16.h>

// CentralSpecificModel: per-species 2-layer MLP (256 -> 1024 -> 256), 4 species,
// N=65536 rows, fp32 in/out. Bucket rows by species; fused per-64-row-tile
// kernel does GEMM1+silu+GEMM2 with bf16 MFMA (16x16x32).
// R3: (a) count_fill rewritten: 32 blocks x 2048 rows, block-internal two-pass
// histogram -> atomic chains 256-deep -> 32-deep (was ~60-70us of the 90us
// non-fused gap). (b) fused kernel operand-SWAP: weights feed MFMA as A,
// X/H as B, computing H^T / Y^T. A/B frag layouts are mutual transposes, so
// weight swizzle + all LDS READ patterns are unchanged, but lanes now hold 4
// consecutive hid/out values -> Hs writes are packed ds_write_b64 (was 4x b16)
// and epilogue is float4 global stores (was scalar). (c) silu uses
// __builtin_amdgcn_rcpf (kills v_div sequence). (d) biases folded into
// accumulator init. (e) XCD swizzle: species s -> XCD pair {2s,2s+1} so each
// XCD's L2 holds only 1MB of weight frags.

#define N_ATOMS 65536
#define D_IN 256
#define D_HID 1024
#define D_OUT 256
#define TPS 1024   // max 64-row tiles per species (worst case: all rows one species)

typedef __attribute__((ext_vector_type(8))) short short8;
typedef __attribute__((ext_vector_type(4))) short short4v;
typedef __attribute__((ext_vector_type(4))) float float4e;

// ws layout (bytes):
//   [0, 256)           cnt[4] padded: cnt[s] at int offset s*16 (64B apart)
//   [256, 1048832)     bucket[4][65536] int
//   [1048832, 3145984) W1 swizzled bf16 fragments (4*256*1024)
//   [3145984, 5243136) W2 swizzled bf16 fragments (4*1024*256)
#define WS_BUCKET_OFF 256
#define WS_W1_OFF 1048832
#define WS_W2_OFF 3145984

__device__ __forceinline__ short f2bf(float f) {
  unsigned u = __builtin_bit_cast(unsigned, f);
  unsigned r = (u + 0x7FFFu + ((u >> 16) & 1u)) >> 16;   // round-to-nearest-even
  return (short)r;
}

// Swizzle W1/W2 fp32 -> bf16 MFMA B-fragment order; zero padded counters.
// B-frag (16x16x32): lane l holds B[k0 + 8*(l>>4) + j][nt*16 + (l&15)], j=0..7.
// (Used as the A operand in the swapped fused kernel: identical register
// content, interpreted as A[m = l&15][k] = W^T fragment.)
__global__ void prep_kernel(const float* __restrict__ W1, const float* __restrict__ W2,
                            short* __restrict__ w1sw, short* __restrict__ w2sw,
                            int* __restrict__ cnt) {
  int gid = blockIdx.x * 256 + threadIdx.x;   // 262144 threads
  if (gid < 64) cnt[gid] = 0;
  int lane = gid & 63;
  int lr = lane & 15;
  int lk = (lane >> 4) * 8;
  if (gid < 131072) {            // W1: [4][256][1024], NT=64, KS=8
    int ks = (gid >> 6) & 7;
    int nt = (gid >> 9) & 63;
    int s  = gid >> 15;
    const float* src = W1 + ((size_t)(s * 256 + ks * 32 + lk)) * 1024 + nt * 16 + lr;
    short8 v;
    for (int j = 0; j < 8; ++j) v[j] = f2bf(src[(size_t)j * 1024]);
    *(short8*)(w1sw + (size_t)gid * 8) = v;
  } else {                       // W2: [4][1024][256], NT=16, KS=32
    int g = gid - 131072;
    int kt = (g >> 6) & 31;
    int nt = (g >> 11) & 15;
    int s  = g >> 15;
    const float* src = W2 + ((size_t)(s * 1024 + kt * 32 + lk)) * 256 + nt * 16 + lr;
    short8 v;
    for (int j = 0; j < 8; ++j) v[j] = f2bf(src[(size_t)j * 256]);
    *(short8*)(w2sw + (size_t)g * 8) = v;
  }
}

// Bucket rows by species. 32 blocks x 2048 rows. Two-pass block-internal
// histogram: pass 1 computes per-(iter,wave,species) counts + per-lane ranks;
// ONE atomicAdd per species per block (32-deep chains, ~8x less serialization
// than the previous 256-deep); pass 2 scatters. Bucket order within a species
// is irrelevant (rows are independent), so block order doesn't matter.
#define CF_BLOCKS 32
#define CF_ITERS 8
__global__ void count_fill_kernel(const int* __restrict__ species,
                                  int* __restrict__ cnt, int* __restrict__ bucket) {
  int tid = threadIdx.x;
  int lane = tid & 63, wid = tid >> 6;
  __shared__ int wcnt[CF_ITERS][4][4];   // [iter][wave][species]
  __shared__ int wb[CF_ITERS][4][4];     // exclusive prefix within block
  __shared__ int base_sm[4];
  int sv[CF_ITERS], rk[CF_ITERS];
  unsigned long long below = (1ull << lane) - 1ull;
  int base_i = blockIdx.x * (CF_ITERS * 256);
  #pragma unroll
  for (int it = 0; it < CF_ITERS; ++it) {
    int s = species[base_i + it * 256 + tid] & 3;
    sv[it] = s;
    unsigned long long m0 = __ballot(s == 0);
    unsigned long long m1 = __ballot(s == 1);
    unsigned long long m2 = __ballot(s == 2);
    unsigned long long m3 = __ballot(s == 3);
    unsigned long long ms = (s == 0) ? m0 : (s == 1) ? m1 : (s == 2) ? m2 : m3;
    rk[it] = __popcll(ms & below);
    if (lane == 0) {
      wcnt[it][wid][0] = __popcll(m0);
      wcnt[it][wid][1] = __popcll(m1);
      wcnt[it][wid][2] = __popcll(m2);
      wcnt[it][wid][3] = __popcll(m3);
    }
  }
  __syncthreads();
  if (tid < 4) {
    int ss = tid, run = 0;
    for (int it = 0; it < CF_ITERS; ++it)
      for (int w = 0; w < 4; ++w) {
        wb[it][w][ss] = run;
        run += wcnt[it][w][ss];
      }
    base_sm[ss] = atomicAdd(&cnt[ss * 16], run);
  }
  __syncthreads();
  #pragma unroll
  for (int it = 0; it < CF_ITERS; ++it) {
    int ss = sv[it];
    bucket[ss * N_ATOMS + base_sm[ss] + wb[it][wid][ss] + rk[it]] = base_i + it * 256 + tid;
  }
}

// Fused per-tile MLP, swapped-operand form. Block = 256 threads (4 waves),
// tile = 64 rows. GEMM1 computes H^T = W1^T @ X^T via mfma(A=W1frag, B=Xfrag):
// lane holds H[row = l&15][hid = base + (l>>4)*4 + q] -> 4 consecutive hid per
// lane -> packed b64 Hs writes. GEMM2 computes Y^T = W2^T @ H^T: lane holds
// Y[row][out..out+3] -> float4 epilogue stores. All LDS read patterns (b128,
// row-major, same strides) identical to the previous version.
#define XS_STRIDE 280
#define HS_STRIDE 152
__global__ __launch_bounds__(256, 2) void fused_kernel(
    const float* __restrict__ x, const int* __restrict__ cntArr,
    const int* __restrict__ bucket, const short* __restrict__ w1sw,
    const short* __restrict__ w2sw, const float* __restrict__ b1,
    const float* __restrict__ b2, float* __restrict__ out) {
  int bid = blockIdx.x;
  // XCD swizzle: bid%8 round-robins XCDs; give species s to XCD pair {2s,2s+1}
  // so each XCD L2 only holds ~1MB of weight fragments.
  int s = (bid & 7) >> 1;
  int t = ((bid >> 3) << 1) | (bid & 1);
  int cnt = cntArr[s * 16];
  int r0 = t * 64;
  if (r0 >= cnt) return;
  int nrows = min(64, cnt - r0);
  const int* buck = bucket + s * N_ATOMS + r0;

  __shared__ short Xs[64 * XS_STRIDE];
  __shared__ short Hs[2][64 * HS_STRIDE];

  int tid = threadIdx.x;

  // Stage gathered x tile -> bf16 LDS. 2048 8-elem groups / 256 threads.
  for (int i = 0; i < 8; ++i) {
    int id = tid + i * 256;
    int r = id >> 5;          // row 0..63
    int g = id & 31;          // 8-float group
    short8 v = {};
    if (r < nrows) {
      const float4* src = (const float4*)(x + (size_t)buck[r] * D_IN + g * 8);
      float4 f0 = src[0];
      float4 f1 = src[1];
      v[0] = f2bf(f0.x); v[1] = f2bf(f0.y); v[2] = f2bf(f0.z); v[3] = f2bf(f0.w);
      v[4] = f2bf(f1.x); v[5] = f2bf(f1.y); v[6] = f2bf(f1.z); v[7] = f2bf(f1.w);
    }
    *(short8*)(Xs + r * XS_STRIDE + g * 8) = v;
  }

  int lane = tid & 63;
  int wid = tid >> 6;
  int lr = lane & 15;          // row within 16-tile (X-row in swapped form)
  int lk = (lane >> 4) * 8;    // k base within 32-kstep
  int lq = (lane >> 4) * 4;    // hid/out base within 16-tile

  // Row gather indices for the epilogue (per bt tile).
  int rowIdx[4];
  #pragma unroll
  for (int bt = 0; bt < 4; ++bt) {
    int r = bt * 16 + lr;
    rowIdx[bt] = (r < nrows) ? buck[r] : -1;
  }

  // accY init = b2 bias (folded; saves epilogue adds).
  float4e accY[4][4];
  #pragma unroll
  for (int at = 0; at < 4; ++at) {
    float4e bv = *(const float4e*)(b2 + s * D_OUT + wid * 64 + at * 16 + lq);
    #pragma unroll
    for (int bt = 0; bt < 4; ++bt) accY[at][bt] = bv;
  }

  // Preload GEMM1 W1-fragments for c=0 (16 batched loads).
  short8 b1f[16];
  #pragma unroll
  for (int ks = 0; ks < 8; ++ks)
    #pragma unroll
    for (int at = 0; at < 2; ++at) {
      int nt = 0 * 8 + wid * 2 + at;
      b1f[ks * 2 + at] = *(const short8*)(w1sw + ((size_t)((s * 64 + nt) * 8 + ks)) * 512 + lane * 8);
    }

  __syncthreads();   // Xs ready

  for (int c = 0; c < 8; ++c) {
    // acc1 init = b1 bias for this chunk's hid slice.
    float4e acc1[2][4];
    #pragma unroll
    for (int at = 0; at < 2; ++at) {
      float4e bv = *(const float4e*)(b1 + s * D_HID + c * 128 + wid * 32 + at * 16 + lq);
      #pragma unroll
      for (int bt = 0; bt < 4; ++bt) acc1[at][bt] = bv;
    }
    // ---- GEMM1: H^T chunk [128 hid x 64 rows] = W1^T @ X^T ----
    #pragma unroll
    for (int ks = 0; ks < 8; ++ks) {
      short8 xb[4];
      #pragma unroll
      for (int bt = 0; bt < 4; ++bt)
        xb[bt] = *(const short8*)(Xs + (bt * 16 + lr) * XS_STRIDE + ks * 32 + lk);
      #pragma unroll
      for (int at = 0; at < 2; ++at)
        #pragma unroll
        for (int bt = 0; bt < 4; ++bt)
          acc1[at][bt] = __builtin_amdgcn_mfma_f32_16x16x32_bf16(b1f[ks * 2 + at], xb[bt], acc1[at][bt], 0, 0, 0);
    }
    // ---- prefetch GEMM2 W2-fragments (latency hidden under silu+barrier) ----
    short8 b2f[16];
    #pragma unroll
    for (int ks = 0; ks < 4; ++ks)
      #pragma unroll
      for (int at = 0; at < 4; ++at) {
        int nt = wid * 4 + at;
        int kt = c * 4 + ks;
        b2f[ks * 4 + at] = *(const short8*)(w2sw + ((size_t)((s * 16 + nt) * 32 + kt)) * 512 + lane * 8);
      }
    // ---- silu -> Hs[c&1], packed b64 writes (4 consecutive hid per lane) ----
    short* hsb = Hs[c & 1];
    #pragma unroll
    for (int at = 0; at < 2; ++at) {
      int hidloc = wid * 32 + at * 16 + lq;
      #pragma unroll
      for (int bt = 0; bt < 4; ++bt) {
        float4e v4 = acc1[at][bt];
        short4v hv;
        #pragma unroll
        for (int q = 0; q < 4; ++q) {
          float pre = v4[q];
          float val = pre * __builtin_amdgcn_rcpf(1.0f + __expf(-pre));  // silu, rcp not div
          hv[q] = f2bf(val);
        }
        *(short4v*)(hsb + (bt * 16 + lr) * HS_STRIDE + hidloc) = hv;
      }
    }
    __syncthreads();   // Hs[c&1] visible; prior readers of Hs[(c+1)&1] done
    // ---- prefetch next chunk's W1-fragments (hidden under GEMM2 MFMA) ----
    if (c < 7) {
      #pragma unroll
      for (int ks = 0; ks < 8; ++ks)
        #pragma unroll
        for (int at = 0; at < 2; ++at) {
          int nt = (c + 1) * 8 + wid * 2 + at;
          b1f[ks * 2 + at] = *(const short8*)(w1sw + ((size_t)((s * 64 + nt) * 8 + ks)) * 512 + lane * 8);
        }
    }
    // ---- GEMM2 partial: Y^T += W2^T @ H^T ----
    #pragma unroll
    for (int ks = 0; ks < 4; ++ks) {
      short8 hb[4];
      #pragma unroll
      for (int bt = 0; bt < 4; ++bt)
        hb[bt] = *(const short8*)(hsb + (bt * 16 + lr) * HS_STRIDE + ks * 32 + lk);
      #pragma unroll
      for (int at = 0; at < 4; ++at)
        #pragma unroll
        for (int bt = 0; bt < 4; ++bt)
          accY[at][bt] = __builtin_amdgcn_mfma_f32_16x16x32_bf16(b2f[ks * 4 + at], hb[bt], accY[at][bt], 0, 0, 0);
    }
  }

  // ---- epilogue: scatter Y rows, 16B per lane (bias already folded in) ----
  #pragma unroll
  for (int at = 0; at < 4; ++at) {
    int nb = wid * 64 + at * 16 + lq;
    #pragma unroll
    for (int bt = 0; bt < 4; ++bt) {
      if (rowIdx[bt] >= 0)
        *(float4e*)(out + (size_t)rowIdx[bt] * D_OUT + nb) = accY[at][bt];
    }
  }
}

extern "C" void kernel_launch(void* const* d_in, const int* in_sizes, int n_in,
                              void* d_out, int out_size, void* d_ws, size_t ws_size,
                              hipStream_t stream) {
  const float* x  = (const float*)d_in[0];
  const int* spc  = (const int*)d_in[1];
  const float* W1 = (const float*)d_in[2];
  const float* b1 = (const float*)d_in[3];
  const float* W2 = (const float*)d_in[4];
  const float* b2 = (const float*)d_in[5];
  float* out = (float*)d_out;

  int*   cnt    = (int*)d_ws;
  int*   bucket = (int*)((char*)d_ws + WS_BUCKET_OFF);
  short* w1sw   = (short*)((char*)d_ws + WS_W1_OFF);
  short* w2sw   = (short*)((char*)d_ws + WS_W2_OFF);

  prep_kernel<<<1024, 256, 0, stream>>>(W1, W2, w1sw, w2sw, cnt);
  count_fill_kernel<<<CF_BLOCKS, 256, 0, stream>>>(spc, cnt, bucket);
  fused_kernel<<<4 * TPS, 256, 0, stream>>>(x, cnt, bucket, w1sw, w2sw, b1, b2, out);
}